// Round 1
// baseline (969.141 us; speedup 1.0000x reference)
//
#include <hip/hip_runtime.h>
#include <math.h>
#include <float.h>

// DeepSeek V3 router: scores = sigmoid(x @ W); grouped top-k routing.
// T=8192, D=7168, E=256, groups=8(x32), topk_groups=4, top_k=8, scale=2.5.
//
// Fused single kernel: each block = 32 token rows x ALL 256 experts, so the
// per-token routing (which needs the full row of 256 scores) runs in the
// epilogue with no global round-trip. fp32 VALU GEMM (no fp32 MFMA on CDNA4);
// sequential-K FMA keeps accumulation deterministic and in the same error
// class as the numpy reference (index tie-break safety).

#define TDIM 8192
#define DDIM 7168
#define EDIM 256
#define BM 32
#define BK 32
#define BMP 36                 // +4 pad: 16B-aligned rows, spreads write banks
#define NTILES (DDIM / BK)     // 224

__global__ __launch_bounds__(256, 1)
void router_fused(const float* __restrict__ X,
                  const float* __restrict__ W,
                  const float* __restrict__ B,
                  float* __restrict__ out)
{
    __shared__ float xs[2][BK][BMP];    // x tile, transposed [k][m]
    __shared__ float ws[2][BK][EDIM];   // W tile, natural [k][n]

    const int t    = threadIdx.x;
    const int lane = t & 63;
    const int wid  = t >> 6;            // wave id 0..3
    const int row0 = blockIdx.x * BM;

    float acc[8][4];
#pragma unroll
    for (int i = 0; i < 8; ++i)
#pragma unroll
        for (int j = 0; j < 4; ++j) acc[i][j] = 0.f;

    // x staging: thread loads x[row0+xm][k0 + xq*4 .. +3] (float4), writes transposed
    const int xm = t >> 3;              // 0..31
    const int xq = t & 7;               // 0..7
    const float* xptr = X + (size_t)(row0 + xm) * DDIM + xq * 4;
    // W staging: iter i loads row k0 + i*4 + wid, cols lane*4..+3
    const float* wptr = W + (size_t)wid * EDIM + lane * 4;

    // ---- prologue: stage tile 0 into buffer 0 ----
    {
        float4 xv = *(const float4*)(xptr);
        float4 wv[8];
#pragma unroll
        for (int i = 0; i < 8; ++i)
            wv[i] = *(const float4*)(wptr + (size_t)i * 4 * EDIM);
        xs[0][xq*4+0][xm] = xv.x;
        xs[0][xq*4+1][xm] = xv.y;
        xs[0][xq*4+2][xm] = xv.z;
        xs[0][xq*4+3][xm] = xv.w;
#pragma unroll
        for (int i = 0; i < 8; ++i)
            *(float4*)&ws[0][i*4 + wid][lane*4] = wv[i];
    }
    __syncthreads();

    // ---- main K loop, double-buffered ----
    for (int tile = 0; tile < NTILES; ++tile) {
        const int cur = tile & 1;
        const int nxt = cur ^ 1;
        float4 xv;
        float4 wv[8];
        const bool has_next = (tile + 1) < NTILES;
        if (has_next) {
            const float* xp = xptr + (size_t)(tile + 1) * BK;
            const float* wp = wptr + (size_t)(tile + 1) * BK * EDIM;
            xv = *(const float4*)xp;
#pragma unroll
            for (int i = 0; i < 8; ++i)
                wv[i] = *(const float4*)(wp + (size_t)i * 4 * EDIM);
        }
        // compute current tile
#pragma unroll
        for (int kk = 0; kk < BK; ++kk) {
            float4 xa = *(const float4*)&xs[cur][kk][wid*8];     // broadcast (wave-uniform)
            float4 xb = *(const float4*)&xs[cur][kk][wid*8 + 4];
            float4 wf = *(const float4*)&ws[cur][kk][lane*4];
            const float xr[8] = {xa.x, xa.y, xa.z, xa.w, xb.x, xb.y, xb.z, xb.w};
            const float wr[4] = {wf.x, wf.y, wf.z, wf.w};
#pragma unroll
            for (int i = 0; i < 8; ++i)
#pragma unroll
                for (int j = 0; j < 4; ++j)
                    acc[i][j] = fmaf(xr[i], wr[j], acc[i][j]);
        }
        if (has_next) {
            xs[nxt][xq*4+0][xm] = xv.x;
            xs[nxt][xq*4+1][xm] = xv.y;
            xs[nxt][xq*4+2][xm] = xv.z;
            xs[nxt][xq*4+3][xm] = xv.w;
#pragma unroll
            for (int i = 0; i < 8; ++i)
                *(float4*)&ws[nxt][i*4 + wid][lane*4] = wv[i];
        }
        __syncthreads();
    }

    // ---- epilogue: sigmoid + routing (each wave owns 8 complete rows) ----
    float4 bv4 = *(const float4*)&B[lane * 4];
    const float bb[4] = {bv4.x, bv4.y, bv4.z, bv4.w};
    const int g = lane >> 3;   // group of this lane's 4 experts (e = lane*4+j)

#pragma unroll
    for (int i = 0; i < 8; ++i) {
        const int tok = row0 + wid * 8 + i;
        float v[4], s[4];
#pragma unroll
        for (int j = 0; j < 4; ++j) {
            v[j] = 1.f / (1.f + expf(-acc[i][j]));   // original sigmoid score
            s[j] = v[j] + bb[j];                     // biased selection score
        }
        // per-lane top-2 of its 4 biased scores
        float t1 = s[0], t2 = -FLT_MAX;
#pragma unroll
        for (int j = 1; j < 4; ++j) {
            if (s[j] > t1) { t2 = t1; t1 = s[j]; }
            else if (s[j] > t2) t2 = s[j];
        }
        // merge top-2 across the 8 lanes of the group (experts 32 per group)
#pragma unroll
        for (int d = 1; d < 8; d <<= 1) {
            float o1 = __shfl_xor(t1, d);
            float o2 = __shfl_xor(t2, d);
            float n1 = fmaxf(t1, o1);
            float n2 = fmaxf(fminf(t1, o1), fmaxf(t2, o2));
            t1 = n1; t2 = n2;
        }
        const float gsc = t1 + t2;   // group score (same add order as reference)
        // gather all 8 group scores to every lane
        float gs[8];
#pragma unroll
        for (int q = 0; q < 8; ++q) gs[q] = __shfl(gsc, q * 8);
        // top-4 groups, ties -> lower group index
        int gmask = 0;
#pragma unroll
        for (int it = 0; it < 4; ++it) {
            float bvv = -FLT_MAX; int bg = 0;
#pragma unroll
            for (int q = 0; q < 8; ++q) {
                const bool avail = ((gmask >> q) & 1) == 0;
                if (avail && gs[q] > bvv) { bvv = gs[q]; bg = q; }
            }
            gmask |= (1 << bg);
        }
        if (((gmask >> g) & 1) == 0) { s[0] = 0.f; s[1] = 0.f; s[2] = 0.f; s[3] = 0.f; }

        // top-8 experts: lexicographic wave argmax (value desc, index asc),
        // carrying the original sigmoid for the weight gather
        float wk[8]; int ik[8]; float wsum = 0.f;
#pragma unroll
        for (int it = 0; it < 8; ++it) {
            float bvv = s[0]; int bi = lane * 4; float bs = v[0];
#pragma unroll
            for (int j = 1; j < 4; ++j)
                if (s[j] > bvv) { bvv = s[j]; bi = lane * 4 + j; bs = v[j]; }
#pragma unroll
            for (int d = 1; d < 64; d <<= 1) {
                float ov = __shfl_xor(bvv, d);
                int   oi = __shfl_xor(bi, d);
                float os = __shfl_xor(bs, d);
                if (ov > bvv || (ov == bvv && oi < bi)) { bvv = ov; bi = oi; bs = os; }
            }
            wk[it] = bs; ik[it] = bi; wsum += bs;
#pragma unroll
            for (int j = 0; j < 4; ++j)
                if (bi == lane * 4 + j) s[j] = -FLT_MAX;   // remove selected
        }
        const float den = wsum + 1e-20f;
        if (lane == 0) {
#pragma unroll
            for (int q = 0; q < 8; ++q) {
                out[(size_t)tok * 8 + q] = wk[q] / den * 2.5f;
                out[(size_t)TDIM * 8 + (size_t)tok * 8 + q] = (float)ik[q];
            }
        }
    }
}

extern "C" void kernel_launch(void* const* d_in, const int* in_sizes, int n_in,
                              void* d_out, int out_size, void* d_ws, size_t ws_size,
                              hipStream_t stream)
{
    (void)in_sizes; (void)n_in; (void)d_ws; (void)ws_size; (void)out_size;
    const float* x    = (const float*)d_in[0];
    const float* kern = (const float*)d_in[1];
    const float* bias = (const float*)d_in[2];
    float* out = (float*)d_out;
    router_fused<<<TDIM / BM, 256, 0, stream>>>(x, kern, bias, out);
}

// Round 2
// 460.219 us; speedup vs baseline: 2.1058x; 2.1058x over previous
//
#include <hip/hip_runtime.h>
#include <math.h>
#include <float.h>

// DeepSeek V3 router, round 2.
// Stage 1: split-K fp32 GEMM (VALU; no fp32 MFMA on CDNA4) -> partial sums in d_ws.
//   BM=64 rows x E=256 cols per block, BK=16, double-buffered LDS, all staging
//   via global_load_lds (W: 16B/lane; x: 4B/lane row-gather = free transpose).
//   acc[16][4] per thread: 64 FMA per kk vs 1 per-lane ds_read_b128 + 4
//   wave-uniform (broadcast) b128 -> LDS pipe stays under VALU/4 budget.
//   split-K -> grid 1024 (4 blocks/CU, up to 4 waves/SIMD) to hide LDS latency.
// Stage 2: tiny reduce+route kernel (deterministic sequential partial add,
//   sigmoid, grouped top-k with jax tie semantics), same routing code that
//   already validated index-exactly.

#define TDIM 8192
#define DDIM 7168
#define EDIM 256
#define BM   64
#define BK   16

typedef const __attribute__((address_space(1))) void* gas_t;
typedef __attribute__((address_space(3))) void* las_t;

__global__ __launch_bounds__(256, 3)
void gemm_partial(const float* __restrict__ X,
                  const float* __restrict__ W,
                  float* __restrict__ P,
                  int splitK, int kLen)
{
    __shared__ float xs[2][BK][BM];     // x transposed [k][m], 4 KB/buf
    __shared__ float ws[2][BK][EDIM];   // W natural [k][e], 16 KB/buf

    const int t    = threadIdx.x;
    const int lane = t & 63;
    const int wid  = t >> 6;
    const int mb   = blockIdx.x / splitK;
    const int ks   = blockIdx.x - mb * splitK;
    const int row0 = mb * BM;
    const int kbeg = ks * kLen;
    const int ntiles = kLen / BK;

    float acc[16][4];
#pragma unroll
    for (int i = 0; i < 16; ++i)
#pragma unroll
        for (int j = 0; j < 4; ++j) acc[i][j] = 0.f;

    const float* xsrc = X + (size_t)(row0 + lane) * DDIM + kbeg;  // per-lane row
    const float* wsrc = W + (size_t)kbeg * EDIM + lane * 4;

    // stage tile into buffer buf: wave wid handles k-rows wid*4 .. wid*4+3
#define STAGE(buf, tile)                                                      \
    {                                                                         \
        const int kof = (tile) * BK + wid * 4;                                \
        _Pragma("unroll")                                                     \
        for (int i = 0; i < 4; ++i) {                                         \
            __builtin_amdgcn_global_load_lds(                                 \
                (gas_t)(xsrc + kof + i),                                      \
                (las_t)&xs[buf][wid * 4 + i][0], 4, 0, 0);                    \
            __builtin_amdgcn_global_load_lds(                                 \
                (gas_t)(wsrc + (size_t)(kof + i) * EDIM),                     \
                (las_t)&ws[buf][wid * 4 + i][0], 16, 0, 0);                   \
        }                                                                     \
    }

    STAGE(0, 0);
    __syncthreads();

    for (int tile = 0; tile < ntiles; ++tile) {
        const int cur = tile & 1;
        const int nxt = cur ^ 1;
        if (tile + 1 < ntiles) STAGE(nxt, tile + 1);
#pragma unroll
        for (int kk = 0; kk < BK; ++kk) {
            const float4 wv = *(const float4*)&ws[cur][kk][lane << 2];
            const float* xp = &xs[cur][kk][wid << 4];
            float xr[16];
#pragma unroll
            for (int q = 0; q < 4; ++q) {
                const float4 xv = *(const float4*)(xp + q * 4);  // broadcast
                xr[q * 4 + 0] = xv.x; xr[q * 4 + 1] = xv.y;
                xr[q * 4 + 2] = xv.z; xr[q * 4 + 3] = xv.w;
            }
            const float wr[4] = {wv.x, wv.y, wv.z, wv.w};
#pragma unroll
            for (int i = 0; i < 16; ++i)
#pragma unroll
                for (int j = 0; j < 4; ++j)
                    acc[i][j] = fmaf(xr[i], wr[j], acc[i][j]);
        }
        __syncthreads();
    }

    // write partials: thread owns rows row0 + wid*16 + i, cols lane*4..+3
    float* Pp = P + ((size_t)ks * TDIM + row0 + wid * 16) * EDIM + lane * 4;
#pragma unroll
    for (int i = 0; i < 16; ++i) {
        float4 v = {acc[i][0], acc[i][1], acc[i][2], acc[i][3]};
        *(float4*)(Pp + (size_t)i * EDIM) = v;
    }
}

// ---- stage 2: reduce partials + sigmoid + grouped top-k routing ----
__global__ __launch_bounds__(256, 4)
void route_kernel(const float* __restrict__ P,
                  const float* __restrict__ B,
                  float* __restrict__ out,
                  int splitK)
{
    const int t    = threadIdx.x;
    const int lane = t & 63;
    const int wid  = t >> 6;
    const int tok0 = blockIdx.x * 32 + wid * 8;

    const float4 bv4 = *(const float4*)&B[lane * 4];
    const float bb[4] = {bv4.x, bv4.y, bv4.z, bv4.w};
    const int g = lane >> 3;   // group of this lane's 4 experts

#pragma unroll
    for (int i = 0; i < 8; ++i) {
        const int tok = tok0 + i;
        float a[4] = {0.f, 0.f, 0.f, 0.f};
        for (int ksl = 0; ksl < splitK; ++ksl) {   // deterministic order
            const float4 pv =
                *(const float4*)&P[((size_t)ksl * TDIM + tok) * EDIM + lane * 4];
            a[0] += pv.x; a[1] += pv.y; a[2] += pv.z; a[3] += pv.w;
        }
        float v[4], s[4];
#pragma unroll
        for (int j = 0; j < 4; ++j) {
            v[j] = 1.f / (1.f + expf(-a[j]));   // original sigmoid score
            s[j] = v[j] + bb[j];                // biased selection score
        }
        // per-lane top-2 of its 4 biased scores
        float t1 = s[0], t2 = -FLT_MAX;
#pragma unroll
        for (int j = 1; j < 4; ++j) {
            if (s[j] > t1) { t2 = t1; t1 = s[j]; }
            else if (s[j] > t2) t2 = s[j];
        }
        // merge top-2 across the 8 lanes of the group
#pragma unroll
        for (int d = 1; d < 8; d <<= 1) {
            float o1 = __shfl_xor(t1, d);
            float o2 = __shfl_xor(t2, d);
            float n1 = fmaxf(t1, o1);
            float n2 = fmaxf(fminf(t1, o1), fmaxf(t2, o2));
            t1 = n1; t2 = n2;
        }
        const float gsc = t1 + t2;
        float gs[8];
#pragma unroll
        for (int q = 0; q < 8; ++q) gs[q] = __shfl(gsc, q * 8);
        // top-4 groups, ties -> lower group index
        int gmask = 0;
#pragma unroll
        for (int it = 0; it < 4; ++it) {
            float bvv = -FLT_MAX; int bg = 0;
#pragma unroll
            for (int q = 0; q < 8; ++q) {
                const bool avail = ((gmask >> q) & 1) == 0;
                if (avail && gs[q] > bvv) { bvv = gs[q]; bg = q; }
            }
            gmask |= (1 << bg);
        }
        if (((gmask >> g) & 1) == 0) { s[0] = 0.f; s[1] = 0.f; s[2] = 0.f; s[3] = 0.f; }

        // top-8 experts: lexicographic wave argmax (value desc, index asc)
        float wk[8]; int ik[8]; float wsum = 0.f;
#pragma unroll
        for (int it = 0; it < 8; ++it) {
            float bvv = s[0]; int bi = lane * 4; float bs = v[0];
#pragma unroll
            for (int j = 1; j < 4; ++j)
                if (s[j] > bvv) { bvv = s[j]; bi = lane * 4 + j; bs = v[j]; }
#pragma unroll
            for (int d = 1; d < 64; d <<= 1) {
                float ov = __shfl_xor(bvv, d);
                int   oi = __shfl_xor(bi, d);
                float os = __shfl_xor(bs, d);
                if (ov > bvv || (ov == bvv && oi < bi)) { bvv = ov; bi = oi; bs = os; }
            }
            wk[it] = bs; ik[it] = bi; wsum += bs;
#pragma unroll
            for (int j = 0; j < 4; ++j)
                if (bi == lane * 4 + j) s[j] = -FLT_MAX;
        }
        const float den = wsum + 1e-20f;
        if (lane == 0) {
#pragma unroll
            for (int q = 0; q < 8; ++q) {
                out[(size_t)tok * 8 + q] = wk[q] / den * 2.5f;
                out[(size_t)TDIM * 8 + (size_t)tok * 8 + q] = (float)ik[q];
            }
        }
    }
}

extern "C" void kernel_launch(void* const* d_in, const int* in_sizes, int n_in,
                              void* d_out, int out_size, void* d_ws, size_t ws_size,
                              hipStream_t stream)
{
    (void)in_sizes; (void)n_in; (void)out_size;
    const float* x    = (const float*)d_in[0];
    const float* kern = (const float*)d_in[1];
    const float* bias = (const float*)d_in[2];
    float* out = (float*)d_out;
    float* P   = (float*)d_ws;

    int splitK = 8;
    while (splitK > 1 && (size_t)splitK * TDIM * EDIM * 4 > ws_size) splitK >>= 1;
    const int kLen = DDIM / splitK;

    gemm_partial<<<(TDIM / BM) * splitK, 256, 0, stream>>>(x, kern, P, splitK, kLen);
    route_kernel<<<TDIM / 32, 256, 0, stream>>>(P, bias, out, splitK);
}

// Round 3
// 230.096 us; speedup vs baseline: 4.2119x; 2.0001x over previous
//
#include <hip/hip_runtime.h>
#include <math.h>
#include <float.h>

// DeepSeek V3 router, round 3: split-fp16 MFMA emulation of the fp32 GEMM.
// x@W via 3 MFMA passes: X0W0 + 2^-11(X1W0 + X0W1), planes pre-scaled by
// powers of 2 so every plane is normal-range fp16 (no denormal flush).
// Error class ~= fp32 GEMM (dropped terms <= 2^-22 rel/product).
//  K1: convert+transpose W -> 2 fp16 planes [E][K] in ws
//  K2: GEMM 128x128 tile, 4 waves, BK=32, dbuf LDS (80B padded rows),
//      splitK=2 -> 256 blocks; fp32 partials in ws
//  K3: reduce partials + sigmoid + grouped top-k route (validated in R1/R2)

#define TDIM 8192
#define DDIM 7168
#define EDIM 256
#define SPLITK 2
#define KSLICE (DDIM / SPLITK)   // 3584
#define NT (KSLICE / 32)         // 112 k-steps
#define LDK 40                   // padded LDS row: 32 halfs + 8 pad = 80 B

typedef _Float16 h8 __attribute__((ext_vector_type(8)));
typedef _Float16 h4 __attribute__((ext_vector_type(4)));
typedef float f4 __attribute__((ext_vector_type(4)));

// ---------------- K1: W -> 2 transposed fp16 planes ----------------
__global__ __launch_bounds__(256)
void convert_w(const float* __restrict__ W,
               _Float16* __restrict__ Wt0, _Float16* __restrict__ Wt1)
{
    __shared__ _Float16 l0[64][72];
    __shared__ _Float16 l1[64][72];
    const int t = threadIdx.x;
    const int kt = blockIdx.x * 64;   // K tile
    const int et = blockIdx.y * 64;   // E tile
#pragma unroll
    for (int i = 0; i < 16; ++i) {
        const int kr = (t >> 6) * 16 + i;       // 0..63
        const int ec = t & 63;
        const float w = W[(size_t)(kt + kr) * EDIM + et + ec] * 256.f;
        const _Float16 h0 = (_Float16)w;
        const _Float16 h1 = (_Float16)((w - (float)h0) * 2048.f);
        l0[kr][ec] = h0;
        l1[kr][ec] = h1;
    }
    __syncthreads();
#pragma unroll
    for (int i = 0; i < 16; ++i) {
        const int er = (t >> 6) * 16 + i;       // 0..63
        const int kc = t & 63;
        Wt0[(size_t)(et + er) * DDIM + kt + kc] = l0[kc][er];
        Wt1[(size_t)(et + er) * DDIM + kt + kc] = l1[kc][er];
    }
}

// ---------------- K2: split-fp16 MFMA GEMM ----------------
__global__ __launch_bounds__(256, 2)
void gemm_mfma(const float* __restrict__ X,
               const _Float16* __restrict__ Wt0,
               const _Float16* __restrict__ Wt1,
               float* __restrict__ P)
{
    __shared__ _Float16 sA[2][2][128][LDK];  // [buf][plane][m][k]
    __shared__ _Float16 sB[2][2][128][LDK];  // [buf][plane][e][k]

    const int t    = threadIdx.x;
    const int lane = t & 63;
    const int wid  = t >> 6;
    const int ks   = blockIdx.x & 1;
    const int nb   = (blockIdx.x >> 1) & 1;
    const int mb   = blockIdx.x >> 2;
    const int m0   = mb * 128;
    const int e0   = nb * 128;
    const int kbeg = ks * KSLICE;

    f4 acc0[4][4], acc1[4][4];
#pragma unroll
    for (int i = 0; i < 4; ++i)
#pragma unroll
        for (int j = 0; j < 4; ++j) { acc0[i][j] = (f4)0.f; acc1[i][j] = (f4)0.f; }

    // staging source pointers
    const float* xg = X + (size_t)(m0 + (t >> 3)) * DDIM + kbeg + (t & 7) * 4;
    const _Float16* bg0 = Wt0 + (size_t)(e0 + (t >> 2)) * DDIM + kbeg + (t & 3) * 8;
    const _Float16* bg1 = Wt1 + (size_t)(e0 + (t >> 2)) * DDIM + kbeg + (t & 3) * 8;

    float4 va[4];
    uint4  vb[4];

#define LOADT(kb)                                                             \
    {                                                                         \
        _Pragma("unroll")                                                     \
        for (int p = 0; p < 4; ++p)                                           \
            va[p] = *(const float4*)(xg + (size_t)p * 32 * DDIM + (kb));      \
        vb[0] = *(const uint4*)(bg0 + (kb));                                  \
        vb[1] = *(const uint4*)(bg0 + (size_t)64 * DDIM + (kb));              \
        vb[2] = *(const uint4*)(bg1 + (kb));                                  \
        vb[3] = *(const uint4*)(bg1 + (size_t)64 * DDIM + (kb));              \
    }

#define WRITET(buf)                                                           \
    {                                                                         \
        _Pragma("unroll")                                                     \
        for (int p = 0; p < 4; ++p) {                                         \
            h4 p0, p1;                                                        \
            const float xv[4] = {va[p].x, va[p].y, va[p].z, va[p].w};         \
            _Pragma("unroll")                                                 \
            for (int j = 0; j < 4; ++j) {                                     \
                const _Float16 h0 = (_Float16)xv[j];                          \
                p0[j] = h0;                                                   \
                p1[j] = (_Float16)((xv[j] - (float)h0) * 2048.f);             \
            }                                                                 \
            *(h4*)&sA[buf][0][(t >> 3) + 32 * p][(t & 7) * 4] = p0;           \
            *(h4*)&sA[buf][1][(t >> 3) + 32 * p][(t & 7) * 4] = p1;           \
        }                                                                     \
        *(uint4*)&sB[buf][0][(t >> 2)][(t & 3) * 8]      = vb[0];             \
        *(uint4*)&sB[buf][0][(t >> 2) + 64][(t & 3) * 8] = vb[1];             \
        *(uint4*)&sB[buf][1][(t >> 2)][(t & 3) * 8]      = vb[2];             \
        *(uint4*)&sB[buf][1][(t >> 2) + 64][(t & 3) * 8] = vb[3];             \
    }

    LOADT(0);
    WRITET(0);
    __syncthreads();

    const int fr = (wid >> 1) * 64 + (lane & 15);   // frag row base (A)
    const int fc = (wid & 1) * 64 + (lane & 15);    // frag col base (B)
    const int kq = (lane >> 4) * 8;                 // k offset within frag

    for (int tile = 0; tile < NT; ++tile) {
        const int cur = tile & 1;
        const int nxt = cur ^ 1;
        const bool hn = (tile + 1) < NT;
        if (hn) LOADT((tile + 1) * 32);

        h8 a0[4], a1[4], b0[4], b1[4];
#pragma unroll
        for (int f = 0; f < 4; ++f) {
            a0[f] = *(const h8*)&sA[cur][0][fr + f * 16][kq];
            a1[f] = *(const h8*)&sA[cur][1][fr + f * 16][kq];
            b0[f] = *(const h8*)&sB[cur][0][fc + f * 16][kq];
            b1[f] = *(const h8*)&sB[cur][1][fc + f * 16][kq];
        }
#pragma unroll
        for (int fm = 0; fm < 4; ++fm)
#pragma unroll
            for (int fn = 0; fn < 4; ++fn) {
                acc0[fm][fn] = __builtin_amdgcn_mfma_f32_16x16x32_f16(
                    a0[fm], b0[fn], acc0[fm][fn], 0, 0, 0);
                acc1[fm][fn] = __builtin_amdgcn_mfma_f32_16x16x32_f16(
                    a1[fm], b0[fn], acc1[fm][fn], 0, 0, 0);
                acc1[fm][fn] = __builtin_amdgcn_mfma_f32_16x16x32_f16(
                    a0[fm], b1[fn], acc1[fm][fn], 0, 0, 0);
            }
        if (hn) WRITET(nxt);
        __syncthreads();
    }

    // epilogue: logit = acc0/256 + acc1/(256*2048); store fp32 partial
    const float s0 = 1.f / 256.f, s1 = 1.f / 524288.f;
#pragma unroll
    for (int fm = 0; fm < 4; ++fm)
#pragma unroll
        for (int fn = 0; fn < 4; ++fn) {
            const int gr = m0 + (wid >> 1) * 64 + fm * 16 + (lane >> 4) * 4;
            const int gc = e0 + (wid & 1) * 64 + fn * 16 + (lane & 15);
#pragma unroll
            for (int r = 0; r < 4; ++r) {
                const float v = acc0[fm][fn][r] * s0 + acc1[fm][fn][r] * s1;
                P[((size_t)ks * TDIM + gr + r) * EDIM + gc] = v;
            }
        }
}

// ---------------- K3: reduce + sigmoid + grouped top-k route ----------------
__global__ __launch_bounds__(256, 4)
void route_kernel(const float* __restrict__ P,
                  const float* __restrict__ B,
                  float* __restrict__ out,
                  int splitK)
{
    const int t    = threadIdx.x;
    const int lane = t & 63;
    const int wid  = t >> 6;
    const int tok0 = blockIdx.x * 32 + wid * 8;

    const float4 bv4 = *(const float4*)&B[lane * 4];
    const float bb[4] = {bv4.x, bv4.y, bv4.z, bv4.w};
    const int g = lane >> 3;

#pragma unroll
    for (int i = 0; i < 8; ++i) {
        const int tok = tok0 + i;
        float a[4] = {0.f, 0.f, 0.f, 0.f};
        for (int ksl = 0; ksl < splitK; ++ksl) {
            const float4 pv =
                *(const float4*)&P[((size_t)ksl * TDIM + tok) * EDIM + lane * 4];
            a[0] += pv.x; a[1] += pv.y; a[2] += pv.z; a[3] += pv.w;
        }
        float v[4], s[4];
#pragma unroll
        for (int j = 0; j < 4; ++j) {
            v[j] = 1.f / (1.f + expf(-a[j]));
            s[j] = v[j] + bb[j];
        }
        float t1 = s[0], t2 = -FLT_MAX;
#pragma unroll
        for (int j = 1; j < 4; ++j) {
            if (s[j] > t1) { t2 = t1; t1 = s[j]; }
            else if (s[j] > t2) t2 = s[j];
        }
#pragma unroll
        for (int d = 1; d < 8; d <<= 1) {
            float o1 = __shfl_xor(t1, d);
            float o2 = __shfl_xor(t2, d);
            float n1 = fmaxf(t1, o1);
            float n2 = fmaxf(fminf(t1, o1), fmaxf(t2, o2));
            t1 = n1; t2 = n2;
        }
        const float gsc = t1 + t2;
        float gs[8];
#pragma unroll
        for (int q = 0; q < 8; ++q) gs[q] = __shfl(gsc, q * 8);
        int gmask = 0;
#pragma unroll
        for (int it = 0; it < 4; ++it) {
            float bvv = -FLT_MAX; int bg = 0;
#pragma unroll
            for (int q = 0; q < 8; ++q) {
                const bool avail = ((gmask >> q) & 1) == 0;
                if (avail && gs[q] > bvv) { bvv = gs[q]; bg = q; }
            }
            gmask |= (1 << bg);
        }
        if (((gmask >> g) & 1) == 0) { s[0] = 0.f; s[1] = 0.f; s[2] = 0.f; s[3] = 0.f; }

        float wk[8]; int ik[8]; float wsum = 0.f;
#pragma unroll
        for (int it = 0; it < 8; ++it) {
            float bvv = s[0]; int bi = lane * 4; float bs = v[0];
#pragma unroll
            for (int j = 1; j < 4; ++j)
                if (s[j] > bvv) { bvv = s[j]; bi = lane * 4 + j; bs = v[j]; }
#pragma unroll
            for (int d = 1; d < 64; d <<= 1) {
                float ov = __shfl_xor(bvv, d);
                int   oi = __shfl_xor(bi, d);
                float os = __shfl_xor(bs, d);
                if (ov > bvv || (ov == bvv && oi < bi)) { bvv = ov; bi = oi; bs = os; }
            }
            wk[it] = bs; ik[it] = bi; wsum += bs;
#pragma unroll
            for (int j = 0; j < 4; ++j)
                if (bi == lane * 4 + j) s[j] = -FLT_MAX;
        }
        const float den = wsum + 1e-20f;
        if (lane == 0) {
#pragma unroll
            for (int q = 0; q < 8; ++q) {
                out[(size_t)tok * 8 + q] = wk[q] / den * 2.5f;
                out[(size_t)TDIM * 8 + (size_t)tok * 8 + q] = (float)ik[q];
            }
        }
    }
}

extern "C" void kernel_launch(void* const* d_in, const int* in_sizes, int n_in,
                              void* d_out, int out_size, void* d_ws, size_t ws_size,
                              hipStream_t stream)
{
    (void)in_sizes; (void)n_in; (void)out_size; (void)ws_size;
    const float* x    = (const float*)d_in[0];
    const float* kern = (const float*)d_in[1];
    const float* bias = (const float*)d_in[2];
    float* out = (float*)d_out;

    float* P = (float*)d_ws;                               // 2*8192*256*4 = 16 MB
    _Float16* Wt0 = (_Float16*)((char*)d_ws + ((size_t)SPLITK * TDIM * EDIM * 4));
    _Float16* Wt1 = Wt0 + (size_t)EDIM * DDIM;             // 3.67 MB each

    convert_w<<<dim3(DDIM / 64, EDIM / 64), 256, 0, stream>>>(kern, Wt0, Wt1);
    gemm_mfma<<<(TDIM / 128) * 2 * SPLITK, 256, 0, stream>>>(x, Wt0, Wt1, P);
    route_kernel<<<TDIM / 32, 256, 0, stream>>>(P, bias, out, SPLITK);
}

// Round 4
// 229.318 us; speedup vs baseline: 4.2262x; 1.0034x over previous
//
#include <hip/hip_runtime.h>
#include <math.h>
#include <float.h>

// DeepSeek V3 router, round 4.
// Split-fp16 MFMA GEMM (3 passes: X0W0 + 2^-11(X1W0 + X0W1)), splitK=4 for
// 2 blocks/CU occupancy, 64B LDS rows with granule^row XOR swizzle
// (conflict-free b128), XCD-chunked block remap so the two N-tiles sharing
// an X slice are L2-adjacent. Route kernel validated index-exact in R1-R3.

#define TDIM 8192
#define DDIM 7168
#define EDIM 256

typedef _Float16 h8 __attribute__((ext_vector_type(8)));
typedef _Float16 h4 __attribute__((ext_vector_type(4)));
typedef float f4 __attribute__((ext_vector_type(4)));

// ---------------- K1: W -> 2 transposed fp16 planes ----------------
__global__ __launch_bounds__(256)
void convert_w(const float* __restrict__ W,
               _Float16* __restrict__ Wt0, _Float16* __restrict__ Wt1)
{
    __shared__ _Float16 l0[64][72];
    __shared__ _Float16 l1[64][72];
    const int t = threadIdx.x;
    const int kt = blockIdx.x * 64;   // K tile
    const int et = blockIdx.y * 64;   // E tile
#pragma unroll
    for (int i = 0; i < 16; ++i) {
        const int kr = (t >> 6) * 16 + i;
        const int ec = t & 63;
        const float w = W[(size_t)(kt + kr) * EDIM + et + ec] * 256.f;
        const _Float16 h0 = (_Float16)w;
        const _Float16 h1 = (_Float16)((w - (float)h0) * 2048.f);
        l0[kr][ec] = h0;
        l1[kr][ec] = h1;
    }
    __syncthreads();
#pragma unroll
    for (int i = 0; i < 16; ++i) {
        const int er = (t >> 6) * 16 + i;
        const int kc = t & 63;
        Wt0[(size_t)(et + er) * DDIM + kt + kc] = l0[kc][er];
        Wt1[(size_t)(et + er) * DDIM + kt + kc] = l1[kc][er];
    }
}

// ---------------- K2: split-fp16 MFMA GEMM ----------------
// LDS tiles: [buf][plane][row(128)][half(32)], 64B rows, granule^row swizzle.
__global__ __launch_bounds__(256, 2)
void gemm_mfma(const float* __restrict__ X,
               const _Float16* __restrict__ Wt0,
               const _Float16* __restrict__ Wt1,
               float* __restrict__ P,
               int splitK, int kLen)
{
    __shared__ _Float16 sA[2][2][128][32];  // 32 KB
    __shared__ _Float16 sB[2][2][128][32];  // 32 KB

    const int t    = threadIdx.x;
    const int lane = t & 63;
    const int wid  = t >> 6;

    // XCD-chunked remap: same-XCD blocks get consecutive logical ids.
    const int cpx = gridDim.x >> 3;
    const int L   = (blockIdx.x & 7) * cpx + (blockIdx.x >> 3);
    const int nb  = L & 1;                 // N-tile (pairs share X slice)
    const int r1  = L >> 1;
    const int ks  = r1 % splitK;
    const int mb  = r1 / splitK;
    const int m0  = mb * 128;
    const int e0  = nb * 128;
    const int kbeg = ks * kLen;
    const int ntiles = kLen >> 5;

    f4 acc0[4][4], acc1[4][4];
#pragma unroll
    for (int i = 0; i < 4; ++i)
#pragma unroll
        for (int j = 0; j < 4; ++j) { acc0[i][j] = (f4)0.f; acc1[i][j] = (f4)0.f; }

    const float* xg = X + (size_t)(m0 + (t >> 3)) * DDIM + kbeg + (t & 7) * 4;
    const _Float16* bg0 = Wt0 + (size_t)(e0 + (t >> 2)) * DDIM + kbeg + (t & 3) * 8;
    const _Float16* bg1 = Wt1 + (size_t)(e0 + (t >> 2)) * DDIM + kbeg + (t & 3) * 8;

    // swizzled write columns (halfs)
    const int colA = (((((t & 7) >> 1) ^ (t >> 3)) & 3) << 3) | (((t & 7) & 1) << 2);
    const int rowA = t >> 3;                       // 0..31
    const int colB = ((((t & 3) ^ ((t >> 2) & 3)) & 3) << 3);
    const int rowB = t >> 2;                       // 0..15

    float4 va[4];
    uint4  vb[4];

#define LOADT(kb)                                                             \
    {                                                                         \
        _Pragma("unroll")                                                     \
        for (int p = 0; p < 4; ++p)                                           \
            va[p] = *(const float4*)(xg + (size_t)p * 32 * DDIM + (kb));      \
        vb[0] = *(const uint4*)(bg0 + (kb));                                  \
        vb[1] = *(const uint4*)(bg0 + (size_t)64 * DDIM + (kb));              \
        vb[2] = *(const uint4*)(bg1 + (kb));                                  \
        vb[3] = *(const uint4*)(bg1 + (size_t)64 * DDIM + (kb));              \
    }

#define WRITET(buf)                                                           \
    {                                                                         \
        _Pragma("unroll")                                                     \
        for (int p = 0; p < 4; ++p) {                                         \
            h4 p0, p1;                                                        \
            const float xv[4] = {va[p].x, va[p].y, va[p].z, va[p].w};         \
            _Pragma("unroll")                                                 \
            for (int j = 0; j < 4; ++j) {                                     \
                const _Float16 h0 = (_Float16)xv[j];                          \
                p0[j] = h0;                                                   \
                p1[j] = (_Float16)((xv[j] - (float)h0) * 2048.f);             \
            }                                                                 \
            *(h4*)&sA[buf][0][rowA + 32 * p][colA] = p0;                      \
            *(h4*)&sA[buf][1][rowA + 32 * p][colA] = p1;                      \
        }                                                                     \
        *(uint4*)&sB[buf][0][rowB][colB]      = vb[0];                        \
        *(uint4*)&sB[buf][0][rowB + 64][colB] = vb[1];                        \
        *(uint4*)&sB[buf][1][rowB][colB]      = vb[2];                        \
        *(uint4*)&sB[buf][1][rowB + 64][colB] = vb[3];                        \
    }

    LOADT(0);
    WRITET(0);
    __syncthreads();

    const int fr  = (wid >> 1) * 64 + (lane & 15);          // A frag row base
    const int fc  = (wid & 1) * 64 + (lane & 15);           // B frag row base
    const int kqs = ((((lane >> 4) ^ lane) & 3) << 3);      // swizzled k granule

    for (int tile = 0; tile < ntiles; ++tile) {
        const int cur = tile & 1;
        const int nxt = cur ^ 1;
        const bool hn = (tile + 1) < ntiles;
        if (hn) LOADT((tile + 1) * 32);

        h8 a0[4], a1[4], b0[4], b1[4];
#pragma unroll
        for (int f = 0; f < 4; ++f) {
            a0[f] = *(const h8*)&sA[cur][0][fr + f * 16][kqs];
            a1[f] = *(const h8*)&sA[cur][1][fr + f * 16][kqs];
            b0[f] = *(const h8*)&sB[cur][0][fc + f * 16][kqs];
            b1[f] = *(const h8*)&sB[cur][1][fc + f * 16][kqs];
        }
#pragma unroll
        for (int fm = 0; fm < 4; ++fm)
#pragma unroll
            for (int fn = 0; fn < 4; ++fn) {
                acc0[fm][fn] = __builtin_amdgcn_mfma_f32_16x16x32_f16(
                    a0[fm], b0[fn], acc0[fm][fn], 0, 0, 0);
                acc1[fm][fn] = __builtin_amdgcn_mfma_f32_16x16x32_f16(
                    a1[fm], b0[fn], acc1[fm][fn], 0, 0, 0);
                acc1[fm][fn] = __builtin_amdgcn_mfma_f32_16x16x32_f16(
                    a0[fm], b1[fn], acc1[fm][fn], 0, 0, 0);
            }
        if (hn) WRITET(nxt);
        __syncthreads();
    }

    const float s0 = 1.f / 256.f, s1 = 1.f / 524288.f;
#pragma unroll
    for (int fm = 0; fm < 4; ++fm)
#pragma unroll
        for (int fn = 0; fn < 4; ++fn) {
            const int gr = m0 + (wid >> 1) * 64 + fm * 16 + (lane >> 4) * 4;
            const int gc = e0 + (wid & 1) * 64 + fn * 16 + (lane & 15);
#pragma unroll
            for (int r = 0; r < 4; ++r) {
                const float v = acc0[fm][fn][r] * s0 + acc1[fm][fn][r] * s1;
                P[((size_t)ks * TDIM + gr + r) * EDIM + gc] = v;
            }
        }
}

// ---------------- K3: reduce + sigmoid + grouped top-k route ----------------
__global__ __launch_bounds__(256, 4)
void route_kernel(const float* __restrict__ P,
                  const float* __restrict__ B,
                  float* __restrict__ out,
                  int splitK)
{
    const int t    = threadIdx.x;
    const int lane = t & 63;
    const int wid  = t >> 6;
    const int tok0 = blockIdx.x * 32 + wid * 8;

    const float4 bv4 = *(const float4*)&B[lane * 4];
    const float bb[4] = {bv4.x, bv4.y, bv4.z, bv4.w};
    const int g = lane >> 3;

#pragma unroll
    for (int i = 0; i < 8; ++i) {
        const int tok = tok0 + i;
        float a[4] = {0.f, 0.f, 0.f, 0.f};
        for (int ksl = 0; ksl < splitK; ++ksl) {
            const float4 pv =
                *(const float4*)&P[((size_t)ksl * TDIM + tok) * EDIM + lane * 4];
            a[0] += pv.x; a[1] += pv.y; a[2] += pv.z; a[3] += pv.w;
        }
        float v[4], s[4];
#pragma unroll
        for (int j = 0; j < 4; ++j) {
            v[j] = 1.f / (1.f + expf(-a[j]));
            s[j] = v[j] + bb[j];
        }
        float t1 = s[0], t2 = -FLT_MAX;
#pragma unroll
        for (int j = 1; j < 4; ++j) {
            if (s[j] > t1) { t2 = t1; t1 = s[j]; }
            else if (s[j] > t2) t2 = s[j];
        }
#pragma unroll
        for (int d = 1; d < 8; d <<= 1) {
            float o1 = __shfl_xor(t1, d);
            float o2 = __shfl_xor(t2, d);
            float n1 = fmaxf(t1, o1);
            float n2 = fmaxf(fminf(t1, o1), fmaxf(t2, o2));
            t1 = n1; t2 = n2;
        }
        const float gsc = t1 + t2;
        float gs[8];
#pragma unroll
        for (int q = 0; q < 8; ++q) gs[q] = __shfl(gsc, q * 8);
        int gmask = 0;
#pragma unroll
        for (int it = 0; it < 4; ++it) {
            float bvv = -FLT_MAX; int bg = 0;
#pragma unroll
            for (int q = 0; q < 8; ++q) {
                const bool avail = ((gmask >> q) & 1) == 0;
                if (avail && gs[q] > bvv) { bvv = gs[q]; bg = q; }
            }
            gmask |= (1 << bg);
        }
        if (((gmask >> g) & 1) == 0) { s[0] = 0.f; s[1] = 0.f; s[2] = 0.f; s[3] = 0.f; }

        float wk[8]; int ik[8]; float wsum = 0.f;
#pragma unroll
        for (int it = 0; it < 8; ++it) {
            float bvv = s[0]; int bi = lane * 4; float bs = v[0];
#pragma unroll
            for (int j = 1; j < 4; ++j)
                if (s[j] > bvv) { bvv = s[j]; bi = lane * 4 + j; bs = v[j]; }
#pragma unroll
            for (int d = 1; d < 64; d <<= 1) {
                float ov = __shfl_xor(bvv, d);
                int   oi = __shfl_xor(bi, d);
                float os = __shfl_xor(bs, d);
                if (ov > bvv || (ov == bvv && oi < bi)) { bvv = ov; bi = oi; bs = os; }
            }
            wk[it] = bs; ik[it] = bi; wsum += bs;
#pragma unroll
            for (int j = 0; j < 4; ++j)
                if (bi == lane * 4 + j) s[j] = -FLT_MAX;
        }
        const float den = wsum + 1e-20f;
        if (lane == 0) {
#pragma unroll
            for (int q = 0; q < 8; ++q) {
                out[(size_t)tok * 8 + q] = wk[q] / den * 2.5f;
                out[(size_t)TDIM * 8 + (size_t)tok * 8 + q] = (float)ik[q];
            }
        }
    }
}

extern "C" void kernel_launch(void* const* d_in, const int* in_sizes, int n_in,
                              void* d_out, int out_size, void* d_ws, size_t ws_size,
                              hipStream_t stream)
{
    (void)in_sizes; (void)n_in; (void)out_size;
    const float* x    = (const float*)d_in[0];
    const float* kern = (const float*)d_in[1];
    const float* bias = (const float*)d_in[2];
    float* out = (float*)d_out;

    const size_t planeBytes = (size_t)EDIM * DDIM * sizeof(_Float16);  // 3.67 MB
    int splitK = 4;
    while (splitK > 1 &&
           (size_t)splitK * TDIM * EDIM * 4 + 2 * planeBytes > ws_size)
        splitK >>= 1;

    float* P = (float*)d_ws;
    _Float16* Wt0 = (_Float16*)((char*)d_ws + (size_t)splitK * TDIM * EDIM * 4);
    _Float16* Wt1 = Wt0 + (size_t)EDIM * DDIM;

    convert_w<<<dim3(DDIM / 64, EDIM / 64), 256, 0, stream>>>(kern, Wt0, Wt1);
    gemm_mfma<<<(TDIM / 128) * 2 * splitK, 256, 0, stream>>>(
        x, Wt0, Wt1, P, splitK, DDIM / splitK);
    route_kernel<<<TDIM / 32, 256, 0, stream>>>(P, bias, out, splitK);
}

// Round 5
// 177.389 us; speedup vs baseline: 5.4634x; 1.2927x over previous
//
#include <hip/hip_runtime.h>
#include <math.h>
#include <float.h>

// DeepSeek V3 router, round 5.
// Split-fp16 MFMA GEMM (3 passes: X0W0 + 2^-11(X1W0 + X0W1)).
// - LDS swizzle fixed: slot = granule ^ ((row>>2)&3)  -> 2-way max (free).
//   (R4's ^(row&3) left rows r,r+4 on the same bank set: 4-way on every read.)
// - B staging via global_load_lds (16B), swizzle folded into the per-lane
//   GLOBAL address, LDS dest linear (guide rule #21).
// - convert_w vectorized (uint4 in/out via LDS transpose).
// Route kernel validated index-exact in R1-R4.

#define TDIM 8192
#define DDIM 7168
#define EDIM 256

typedef _Float16 h8 __attribute__((ext_vector_type(8)));
typedef _Float16 h4 __attribute__((ext_vector_type(4)));
typedef float f4 __attribute__((ext_vector_type(4)));

typedef const __attribute__((address_space(1))) void* gas_t;
typedef __attribute__((address_space(3))) void* las_t;

// ---------------- K1: W -> 2 transposed fp16 planes [E][K] ----------------
__global__ __launch_bounds__(256)
void convert_w(const float* __restrict__ W,
               _Float16* __restrict__ Wt0, _Float16* __restrict__ Wt1)
{
    __shared__ _Float16 l0[64][80];   // [e][k], 160B rows (16B-aligned)
    __shared__ _Float16 l1[64][80];
    const int t = threadIdx.x;
    const int kt = blockIdx.x * 64;
    const int et = blockIdx.y * 64;
#pragma unroll
    for (int i = 0; i < 16; ++i) {
        const int kr = (t >> 6) * 16 + i;       // 0..63
        const int ec = t & 63;
        const float w = W[(size_t)(kt + kr) * EDIM + et + ec] * 256.f;
        const _Float16 h0 = (_Float16)w;
        const _Float16 h1 = (_Float16)((w - (float)h0) * 2048.f);
        l0[ec][kr] = h0;                        // transposed in LDS
        l1[ec][kr] = h1;
    }
    __syncthreads();
#pragma unroll
    for (int j = 0; j < 2; ++j) {
        const int er = t >> 2;                  // 0..63
        const int kc = ((t & 3) + 4 * j) * 8;   // 0..56 step 8
        const uint4 v0 = *(const uint4*)&l0[er][kc];
        const uint4 v1 = *(const uint4*)&l1[er][kc];
        *(uint4*)&Wt0[(size_t)(et + er) * DDIM + kt + kc] = v0;
        *(uint4*)&Wt1[(size_t)(et + er) * DDIM + kt + kc] = v1;
    }
}

// ---------------- K2: split-fp16 MFMA GEMM ----------------
// LDS tiles [buf][plane][row(128)][32 halfs]; 16B slot s of row r holds
// original granule s ^ ((r>>2)&3).
__global__ __launch_bounds__(256, 2)
void gemm_mfma(const float* __restrict__ X,
               const _Float16* __restrict__ Wt0,
               const _Float16* __restrict__ Wt1,
               float* __restrict__ P,
               int splitK, int kLen)
{
    __shared__ _Float16 sA[2][2][128][32];  // 32 KB
    __shared__ _Float16 sB[2][2][128][32];  // 32 KB

    const int t    = threadIdx.x;
    const int lane = t & 63;
    const int wid  = t >> 6;

    // XCD-chunked remap (grid is a multiple of 8 for all splitK in {1,2,4}).
    const int cpx = gridDim.x >> 3;
    const int L   = (blockIdx.x & 7) * cpx + (blockIdx.x >> 3);
    const int nb  = L & 1;                 // N-tile pairs share the X slice
    const int r1  = L >> 1;
    const int ks  = r1 % splitK;
    const int mb  = r1 / splitK;
    const int m0  = mb * 128;
    const int e0  = nb * 128;
    const int kbeg = ks * kLen;
    const int ntiles = kLen >> 5;

    f4 acc0[4][4], acc1[4][4];
#pragma unroll
    for (int i = 0; i < 4; ++i)
#pragma unroll
        for (int j = 0; j < 4; ++j) { acc0[i][j] = (f4)0.f; acc1[i][j] = (f4)0.f; }

    // ---- A staging (reg: needs fp32->2xfp16 conversion) ----
    const float* xg = X + (size_t)(m0 + (t >> 3)) * DDIM + kbeg + (t & 7) * 4;
    const int rowA = t >> 3;                                   // +32p
    const int colA = (((((t & 7) >> 1) ^ ((t >> 5) & 3)) & 3) << 3)
                   | ((t & 1) << 2);

    // ---- B staging (DMA): wave covers plane wid>>1, rows ((wid&1)*4+i)*16 ----
    const _Float16* bsrc[4];
    {
        const int gsw = (((lane & 3) ^ ((lane >> 4) & 3)) & 3) * 8;
        const _Float16* wp = (wid >> 1) ? Wt1 : Wt0;
#pragma unroll
        for (int i = 0; i < 4; ++i) {
            const int br = ((wid & 1) * 4 + i) * 16;
            bsrc[i] = wp + (size_t)(e0 + br + (lane >> 2)) * DDIM + kbeg + gsw;
        }
    }

    float4 va[4];

#define DMAB(buf, kb)                                                         \
    {                                                                         \
        _Pragma("unroll")                                                     \
        for (int i = 0; i < 4; ++i)                                           \
            __builtin_amdgcn_global_load_lds(                                 \
                (gas_t)(bsrc[i] + (kb)),                                      \
                (las_t)&sB[buf][wid >> 1][((wid & 1) * 4 + i) * 16][0],       \
                16, 0, 0);                                                    \
    }

#define LOADA(kb)                                                             \
    {                                                                         \
        _Pragma("unroll")                                                     \
        for (int p = 0; p < 4; ++p)                                           \
            va[p] = *(const float4*)(xg + (size_t)p * 32 * DDIM + (kb));      \
    }

#define WRITEA(buf)                                                           \
    {                                                                         \
        _Pragma("unroll")                                                     \
        for (int p = 0; p < 4; ++p) {                                         \
            h4 p0, p1;                                                        \
            const float xv[4] = {va[p].x, va[p].y, va[p].z, va[p].w};         \
            _Pragma("unroll")                                                 \
            for (int j = 0; j < 4; ++j) {                                     \
                const _Float16 h0 = (_Float16)xv[j];                          \
                p0[j] = h0;                                                   \
                p1[j] = (_Float16)((xv[j] - (float)h0) * 2048.f);             \
            }                                                                 \
            *(h4*)&sA[buf][0][rowA + 32 * p][colA] = p0;                      \
            *(h4*)&sA[buf][1][rowA + 32 * p][colA] = p1;                      \
        }                                                                     \
    }

    DMAB(0, 0);
    LOADA(0);
    WRITEA(0);
    __syncthreads();

    const int fr  = (wid >> 1) * 64 + (lane & 15);              // A frag row
    const int fc  = (wid & 1) * 64 + (lane & 15);               // B frag row
    const int kqs = (((lane >> 4) ^ (lane >> 2)) & 3) << 3;     // swizzled slot

    for (int tile = 0; tile < ntiles; ++tile) {
        const int cur = tile & 1;
        const int nxt = cur ^ 1;
        const bool hn = (tile + 1) < ntiles;
        if (hn) {
            DMAB(nxt, (tile + 1) * 32);
            LOADA((tile + 1) * 32);
        }

        h8 a0[4], a1[4], b0[4], b1[4];
#pragma unroll
        for (int f = 0; f < 4; ++f) {
            a0[f] = *(const h8*)&sA[cur][0][fr + f * 16][kqs];
            a1[f] = *(const h8*)&sA[cur][1][fr + f * 16][kqs];
            b0[f] = *(const h8*)&sB[cur][0][fc + f * 16][kqs];
            b1[f] = *(const h8*)&sB[cur][1][fc + f * 16][kqs];
        }
#pragma unroll
        for (int fm = 0; fm < 4; ++fm)
#pragma unroll
            for (int fn = 0; fn < 4; ++fn) {
                acc0[fm][fn] = __builtin_amdgcn_mfma_f32_16x16x32_f16(
                    a0[fm], b0[fn], acc0[fm][fn], 0, 0, 0);
                acc1[fm][fn] = __builtin_amdgcn_mfma_f32_16x16x32_f16(
                    a1[fm], b0[fn], acc1[fm][fn], 0, 0, 0);
                acc1[fm][fn] = __builtin_amdgcn_mfma_f32_16x16x32_f16(
                    a0[fm], b1[fn], acc1[fm][fn], 0, 0, 0);
            }
        if (hn) WRITEA(nxt);
        __syncthreads();
    }

    const float s0 = 1.f / 256.f, s1 = 1.f / 524288.f;
#pragma unroll
    for (int fm = 0; fm < 4; ++fm)
#pragma unroll
        for (int fn = 0; fn < 4; ++fn) {
            const int gr = m0 + (wid >> 1) * 64 + fm * 16 + (lane >> 4) * 4;
            const int gc = e0 + (wid & 1) * 64 + fn * 16 + (lane & 15);
#pragma unroll
            for (int r = 0; r < 4; ++r) {
                const float v = acc0[fm][fn][r] * s0 + acc1[fm][fn][r] * s1;
                P[((size_t)ks * TDIM + gr + r) * EDIM + gc] = v;
            }
        }
}

// ---------------- K3: reduce + sigmoid + grouped top-k route ----------------
__global__ __launch_bounds__(256, 4)
void route_kernel(const float* __restrict__ P,
                  const float* __restrict__ B,
                  float* __restrict__ out,
                  int splitK)
{
    const int t    = threadIdx.x;
    const int lane = t & 63;
    const int wid  = t >> 6;
    const int tok0 = blockIdx.x * 32 + wid * 8;

    const float4 bv4 = *(const float4*)&B[lane * 4];
    const float bb[4] = {bv4.x, bv4.y, bv4.z, bv4.w};
    const int g = lane >> 3;

#pragma unroll
    for (int i = 0; i < 8; ++i) {
        const int tok = tok0 + i;
        float a[4] = {0.f, 0.f, 0.f, 0.f};
        for (int ksl = 0; ksl < splitK; ++ksl) {
            const float4 pv =
                *(const float4*)&P[((size_t)ksl * TDIM + tok) * EDIM + lane * 4];
            a[0] += pv.x; a[1] += pv.y; a[2] += pv.z; a[3] += pv.w;
        }
        float v[4], s[4];
#pragma unroll
        for (int j = 0; j < 4; ++j) {
            v[j] = 1.f / (1.f + expf(-a[j]));
            s[j] = v[j] + bb[j];
        }
        float t1 = s[0], t2 = -FLT_MAX;
#pragma unroll
        for (int j = 1; j < 4; ++j) {
            if (s[j] > t1) { t2 = t1; t1 = s[j]; }
            else if (s[j] > t2) t2 = s[j];
        }
#pragma unroll
        for (int d = 1; d < 8; d <<= 1) {
            float o1 = __shfl_xor(t1, d);
            float o2 = __shfl_xor(t2, d);
            float n1 = fmaxf(t1, o1);
            float n2 = fmaxf(fminf(t1, o1), fmaxf(t2, o2));
            t1 = n1; t2 = n2;
        }
        const float gsc = t1 + t2;
        float gs[8];
#pragma unroll
        for (int q = 0; q < 8; ++q) gs[q] = __shfl(gsc, q * 8);
        int gmask = 0;
#pragma unroll
        for (int it = 0; it < 4; ++it) {
            float bvv = -FLT_MAX; int bg = 0;
#pragma unroll
            for (int q = 0; q < 8; ++q) {
                const bool avail = ((gmask >> q) & 1) == 0;
                if (avail && gs[q] > bvv) { bvv = gs[q]; bg = q; }
            }
            gmask |= (1 << bg);
        }
        if (((gmask >> g) & 1) == 0) { s[0] = 0.f; s[1] = 0.f; s[2] = 0.f; s[3] = 0.f; }

        float wk[8]; int ik[8]; float wsum = 0.f;
#pragma unroll
        for (int it = 0; it < 8; ++it) {
            float bvv = s[0]; int bi = lane * 4; float bs = v[0];
#pragma unroll
            for (int j = 1; j < 4; ++j)
                if (s[j] > bvv) { bvv = s[j]; bi = lane * 4 + j; bs = v[j]; }
#pragma unroll
            for (int d = 1; d < 64; d <<= 1) {
                float ov = __shfl_xor(bvv, d);
                int   oi = __shfl_xor(bi, d);
                float os = __shfl_xor(bs, d);
                if (ov > bvv || (ov == bvv && oi < bi)) { bvv = ov; bi = oi; bs = os; }
            }
            wk[it] = bs; ik[it] = bi; wsum += bs;
#pragma unroll
            for (int j = 0; j < 4; ++j)
                if (bi == lane * 4 + j) s[j] = -FLT_MAX;
        }
        const float den = wsum + 1e-20f;
        if (lane == 0) {
#pragma unroll
            for (int q = 0; q < 8; ++q) {
                out[(size_t)tok * 8 + q] = wk[q] / den * 2.5f;
                out[(size_t)TDIM * 8 + (size_t)tok * 8 + q] = (float)ik[q];
            }
        }
    }
}

extern "C" void kernel_launch(void* const* d_in, const int* in_sizes, int n_in,
                              void* d_out, int out_size, void* d_ws, size_t ws_size,
                              hipStream_t stream)
{
    (void)in_sizes; (void)n_in; (void)out_size;
    const float* x    = (const float*)d_in[0];
    const float* kern = (const float*)d_in[1];
    const float* bias = (const float*)d_in[2];
    float* out = (float*)d_out;

    const size_t planeBytes = (size_t)EDIM * DDIM * sizeof(_Float16);
    int splitK = 4;
    while (splitK > 1 &&
           (size_t)splitK * TDIM * EDIM * 4 + 2 * planeBytes > ws_size)
        splitK >>= 1;

    float* P = (float*)d_ws;
    _Float16* Wt0 = (_Float16*)((char*)d_ws + (size_t)splitK * TDIM * EDIM * 4);
    _Float16* Wt1 = Wt0 + (size_t)EDIM * DDIM;

    convert_w<<<dim3(DDIM / 64, EDIM / 64), 256, 0, stream>>>(kern, Wt0, Wt1);
    gemm_mfma<<<(TDIM / 128) * 2 * splitK, 256, 0, stream>>>(
        x, Wt0, Wt1, P, splitK, DDIM / splitK);
    route_kernel<<<TDIM / 32, 256, 0, stream>>>(P, bias, out, splitK);
}